// Round 7
// baseline (506.700 us; speedup 1.0000x reference)
//
#include <hip/hip_runtime.h>
#include <hip/hip_fp16.h>

// ScaledDotProductAttention: context = softmax(QK^T/sqrt(d) - 100*mask) @ V
// B=32 Tq=2048 Tk=1024 d=128 dv=256, fp32 in/out.
// R7: decomposition into single-phase streaming kernels.
//   cvt_k:   K f32 -> f16 (ws, 8 MB)
//   trans_v: V -> V^T f16 (ws, 16 MB)
//   k1:      QK^T + mask + exp (single interleaved loop; mask stream dominant,
//            MFMA hidden under it). Writes e (f16) into the first 2KB of each
//            score row's 4KB slot in d_out, and 1/rowsum -> ws.
//   k2:      PV from e-gathers + V^T frags (barrier-free MFMA loop), then
//            per-thread reg-staged e->normalized-score stream + ctx epilogue.

namespace {

constexpr int kB = 32, kTq = 2048, kTk = 1024, kD = 128, kDv = 256;
constexpr float kScale = 0.08838834764831845f;  // 1/sqrt(128)

typedef _Float16 half8 __attribute__((ext_vector_type(8)));
typedef _Float16 half4 __attribute__((ext_vector_type(4)));
typedef float    f32x4 __attribute__((ext_vector_type(4)));

// workspace layout (24.3 MB total, same budget as R5/R6 which ran fine)
constexpr size_t kWsK   = 0;          // K16 [32][1024][128] f16 = 8 MiB
constexpr size_t kWsV   = 8388608;    // VT  [32][256][1024] f16 = 16 MiB
constexpr size_t kWsInv = 25165824;   // inv rowsum [32*2048] f32 = 256 KiB

// ---- pre-kernel 1: K f32 -> f16 (R5-proven) ----
__global__ __launch_bounds__(256)
void cvt_k(const float* __restrict__ in, _Float16* __restrict__ out) {
  int i = (blockIdx.x * 256 + threadIdx.x) * 8;
  f32x4 a = *(const f32x4*)(in + i);
  f32x4 b = *(const f32x4*)(in + i + 4);
  half8 h;
  h[0] = a[0]; h[1] = a[1]; h[2] = a[2]; h[3] = a[3];
  h[4] = b[0]; h[5] = b[1]; h[6] = b[2]; h[7] = b[3];
  *(half8*)(out + i) = h;
}

// ---- pre-kernel 2: V [k][dv] f32 -> V^T [dv][k] f16 (R5-proven) ----
__global__ __launch_bounds__(256)
void trans_v(const float* __restrict__ v, _Float16* __restrict__ vt) {
  __shared__ _Float16 t[64 * 66];
  const int b   = blockIdx.x >> 6;
  const int idx = blockIdx.x & 63;
  const int k0  = (idx & 15) * 64;
  const int d0  = (idx >> 4) * 64;
  const int r = threadIdx.x >> 6, c = threadIdx.x & 63;
#pragma unroll 4
  for (int it = 0; it < 16; ++it) {
    float x = v[((size_t)b * kTk + k0 + it * 4 + r) * kDv + d0 + c];
    t[c * 66 + it * 4 + r] = (_Float16)x;
  }
  __syncthreads();
  const int dr = threadIdx.x >> 4, kc = (threadIdx.x & 15) * 4;
#pragma unroll
  for (int it = 0; it < 4; ++it) {
    int drow = it * 16 + dr;
    half4 h;
#pragma unroll
    for (int j = 0; j < 4; ++j) h[j] = t[drow * 66 + kc + j];
    *(half4*)(vt + ((size_t)b * kDv + d0 + drow) * kTk + k0 + kc) = h;
  }
}

// ---- K1: QK^T + mask + exp -> e(f16 in score slots) + 1/rowsum(ws) ----
// wg = 32 q rows x full 1024 k. 8 waves; wave w owns keys w*16+l15 of each
// 128-key step (8 steps). A (Q, rows 0..31) in regs; B (K16) 1-step prefetch
// issued BEFORE mask prefetch so neither wait drains the other (vmcnt order).
__global__ __launch_bounds__(512, 4)
void k1_logits(const float* __restrict__ qg, const _Float16* __restrict__ K16,
               const float* __restrict__ mg, float* __restrict__ out,
               float* __restrict__ inv_ws) {
  __shared__ __align__(16) unsigned char s_[2 * 8192 + 32 * 8 * 4];
  float* part = (float*)(s_ + 16384);

  const int tid  = threadIdx.x;
  const int lane = tid & 63;
  const int wid  = tid >> 6;     // 0..7 : key sub-group within step
  const int l15  = lane & 15;
  const int lg   = lane >> 4;    // 0..3

  const int bi    = blockIdx.x;               // 0..2047
  const int batch = (bi & 7) * 4 + (bi >> 9); // XCD-grouped
  const int q0    = ((bi >> 3) & 63) * 32;

  const float* Q = qg + ((size_t)batch * kTq + q0) * kD;
  const _Float16* Kb = K16 + (size_t)batch * kTk * kD;
  const float* M = mg + ((size_t)batch * kTq + q0) * kTk;
  // e region: first 2KB (1024 f16) of each score row's 4KB slot
  char* Ebase = (char*)(out + (size_t)kB * kTq * kDv) +
                ((size_t)batch * kTq + q0) * 4096;

  // ---- Q fragments: rows 0..31 as two 16-row A-frags ----
  half8 qf[2][4];
#pragma unroll
  for (int h = 0; h < 2; ++h) {
    const float* qrow = Q + (size_t)(h * 16 + l15) * kD + lg * 8;
#pragma unroll
    for (int c = 0; c < 4; ++c) {
      f32x4 a = *(const f32x4*)(qrow + c * 32);
      f32x4 b = *(const f32x4*)(qrow + c * 32 + 4);
      half8 hh;
      hh[0] = a[0]; hh[1] = a[1]; hh[2] = a[2]; hh[3] = a[3];
      hh[4] = b[0]; hh[5] = b[1]; hh[6] = b[2]; hh[7] = b[3];
      qf[h][c] = hh;
    }
  }

  auto ldB = [&](int s, half8* b) {
    const _Float16* p = Kb + (size_t)(s * 128 + wid * 16 + l15) * kD + lg * 8;
    b[0] = *(const half8*)(p);
    b[1] = *(const half8*)(p + 32);
    b[2] = *(const half8*)(p + 64);
    b[3] = *(const half8*)(p + 96);
  };
  auto ldM = [&](int s, float* m) {
#pragma unroll
    for (int h = 0; h < 2; ++h)
#pragma unroll
      for (int j = 0; j < 4; ++j)
        m[h * 4 + j] = M[(size_t)(h * 16 + lg * 4 + j) * kTk +
                         s * 128 + wid * 16 + l15];
  };

  half8 bf[4], bn[4];
  float mv[8], mn[8];
  ldB(0, bf);          // B first,
  ldM(0, mv);          // mask second (vmcnt order discipline)
  float rsum[8] = {0, 0, 0, 0, 0, 0, 0, 0};

  for (int s = 0; s < 8; ++s) {
    if (s + 1 < 8) { ldB(s + 1, bn); ldM(s + 1, mn); }  // issue early
    f32x4 acc0 = {0.f, 0.f, 0.f, 0.f}, acc1 = {0.f, 0.f, 0.f, 0.f};
    __builtin_amdgcn_s_setprio(1);
#pragma unroll
    for (int c = 0; c < 4; ++c) {
      acc0 = __builtin_amdgcn_mfma_f32_16x16x32_f16(qf[0][c], bf[c], acc0, 0, 0, 0);
      acc1 = __builtin_amdgcn_mfma_f32_16x16x32_f16(qf[1][c], bf[c], acc1, 0, 0, 0);
    }
    __builtin_amdgcn_s_setprio(0);
    const int buf = (s & 1) * 8192;
    const int colb = (wid * 16 + l15) * 2;
#pragma unroll
    for (int h = 0; h < 2; ++h)
#pragma unroll
      for (int j = 0; j < 4; ++j) {
        float sc = (h ? acc1[j] : acc0[j]) * kScale - 100.f * mv[h * 4 + j];
        float e = __expf(sc);
        rsum[h * 4 + j] += e;
        int row = h * 16 + lg * 4 + j;
        *(_Float16*)(s_ + buf + row * 256 + (colb ^ ((row & 7) << 4))) =
            (_Float16)e;
      }
    __syncthreads();
    // coalesced e-tile write: 32 rows x 256 B, 16 threads/row x half8
    {
      int row = tid >> 4;
      int cb  = (tid & 15) * 16;
      half8 v = *(const half8*)(s_ + buf + row * 256 + (cb ^ ((row & 7) << 4)));
      *(half8*)(Ebase + (size_t)row * 4096 + s * 256 + cb) = v;
    }
#pragma unroll
    for (int c = 0; c < 4; ++c) bf[c] = bn[c];
#pragma unroll
    for (int j = 0; j < 8; ++j) mv[j] = mn[j];
  }

  // rowsum reduce: 16-lane shfl -> per-wave partials -> 1/sum -> ws
#pragma unroll
  for (int m = 1; m <= 8; m <<= 1)
#pragma unroll
    for (int j = 0; j < 8; ++j) rsum[j] += __shfl_xor(rsum[j], m);
  if (l15 == 0) {
#pragma unroll
    for (int h = 0; h < 2; ++h)
#pragma unroll
      for (int j = 0; j < 4; ++j)
        part[(h * 16 + lg * 4 + j) * 8 + wid] = rsum[h * 4 + j];
  }
  __syncthreads();
  if (tid < 32) {
    float ssum = 0.f;
#pragma unroll
    for (int w = 0; w < 8; ++w) ssum += part[tid * 8 + w];
    inv_ws[(size_t)batch * kTq + q0 + tid] = 1.0f / ssum;
  }
}

// ---- K2: PV (e-gather x V^T frags) + normalized score stream + ctx ----
// wg = 32 q rows x full dv. 8 waves; wave w owns dv [w*32, w*32+32).
// One barrier total (drain e reads before score clobbers e).
__global__ __launch_bounds__(512, 4)
void k2_score_pv(const _Float16* __restrict__ VT,
                 const float* __restrict__ inv_ws, float* __restrict__ out) {
  const int tid  = threadIdx.x;
  const int lane = tid & 63;
  const int wid  = tid >> 6;     // 0..7 : dv group
  const int l15  = lane & 15;
  const int lg   = lane >> 4;    // 0..3

  const int bi    = blockIdx.x;
  const int batch = (bi & 7) * 4 + (bi >> 9);
  const int q0    = ((bi >> 3) & 63) * 32;

  float* CTX = out + ((size_t)batch * kTq + q0) * kDv;
  float* SCR = out + (size_t)kB * kTq * kDv + ((size_t)batch * kTq + q0) * kTk;
  const char* Ebase = (const char*)SCR;       // e f16 at row*4096 + k*2
  const _Float16* Vb = VT + (size_t)batch * kDv * kTk;
  const float* INV = inv_ws + (size_t)batch * kTq + q0;
  const int dv0 = wid * 32;

  auto ldA = [&](int kc, half8* a) {
    a[0] = *(const half8*)(Ebase + (size_t)l15 * 4096 + kc * 64 + lg * 16);
    a[1] = *(const half8*)(Ebase + (size_t)(16 + l15) * 4096 + kc * 64 + lg * 16);
  };
  auto ldV = [&](int kc, half8* b) {
    const _Float16* p = Vb + (size_t)(dv0 + l15) * kTk + kc * 32 + lg * 8;
    b[0] = *(const half8*)(p);
    b[1] = *(const half8*)(p + (size_t)16 * kTk);
  };

  f32x4 acc[2][2];
#pragma unroll
  for (int h = 0; h < 2; ++h)
#pragma unroll
    for (int t = 0; t < 2; ++t) acc[h][t] = (f32x4){0, 0, 0, 0};

  half8 aA[2], bA[2], aB[2], bB[2];
  ldA(0, aA); ldV(0, bA);
  ldA(1, aB); ldV(1, bB);
  for (int kc = 0; kc < 32; kc += 2) {
    __builtin_amdgcn_s_setprio(1);
    acc[0][0] = __builtin_amdgcn_mfma_f32_16x16x32_f16(aA[0], bA[0], acc[0][0], 0, 0, 0);
    acc[1][0] = __builtin_amdgcn_mfma_f32_16x16x32_f16(aA[1], bA[0], acc[1][0], 0, 0, 0);
    acc[0][1] = __builtin_amdgcn_mfma_f32_16x16x32_f16(aA[0], bA[1], acc[0][1], 0, 0, 0);
    acc[1][1] = __builtin_amdgcn_mfma_f32_16x16x32_f16(aA[1], bA[1], acc[1][1], 0, 0, 0);
    __builtin_amdgcn_s_setprio(0);
    if (kc + 2 < 32) { ldA(kc + 2, aA); ldV(kc + 2, bA); }
    __builtin_amdgcn_s_setprio(1);
    acc[0][0] = __builtin_amdgcn_mfma_f32_16x16x32_f16(aB[0], bB[0], acc[0][0], 0, 0, 0);
    acc[1][0] = __builtin_amdgcn_mfma_f32_16x16x32_f16(aB[1], bB[0], acc[1][0], 0, 0, 0);
    acc[0][1] = __builtin_amdgcn_mfma_f32_16x16x32_f16(aB[0], bB[1], acc[0][1], 0, 0, 0);
    acc[1][1] = __builtin_amdgcn_mfma_f32_16x16x32_f16(aB[1], bB[1], acc[1][1], 0, 0, 0);
    __builtin_amdgcn_s_setprio(0);
    if (kc + 3 < 32) { ldA(kc + 3, aB); ldV(kc + 3, bB); }
  }

  __syncthreads();   // all e reads retired before score overwrites the slots

  // score stream: thread owns row tid>>4, col slice (tid&15); read e slice to
  // regs (all loads precede all stores in wave program order; rows are
  // wave-disjoint), then write normalized f32x4.
  {
    const int row = tid >> 4;
    const char* ep = Ebase + (size_t)row * 4096 + (tid & 15) * 8;
    half4 ev[16];
#pragma unroll
    for (int it = 0; it < 16; ++it)
      ev[it] = *(const half4*)(ep + it * 128);
    float inv = INV[row];
    float* sp = SCR + (size_t)row * kTk + (tid & 15) * 4;
#pragma unroll
    for (int it = 0; it < 16; ++it) {
      f32x4 o;
      o[0] = (float)ev[it][0] * inv; o[1] = (float)ev[it][1] * inv;
      o[2] = (float)ev[it][2] * inv; o[3] = (float)ev[it][3] * inv;
      *(f32x4*)(sp + it * 64) = o;
    }
  }

  // ctx epilogue
#pragma unroll
  for (int h = 0; h < 2; ++h)
#pragma unroll
    for (int j = 0; j < 4; ++j) {
      float inv = INV[h * 16 + lg * 4 + j];
      size_t r = (size_t)(h * 16 + lg * 4 + j) * kDv + dv0 + l15;
      CTX[r]      = acc[h][0][j] * inv;
      CTX[r + 16] = acc[h][1][j] * inv;
    }
}

}  // namespace

extern "C" void kernel_launch(void* const* d_in, const int* in_sizes, int n_in,
                              void* d_out, int out_size, void* d_ws, size_t ws_size,
                              hipStream_t stream) {
  const float* q = (const float*)d_in[0];
  const float* k = (const float*)d_in[1];
  const float* v = (const float*)d_in[2];
  const float* m = (const float*)d_in[3];
  float* out = (float*)d_out;
  (void)in_sizes; (void)n_in; (void)out_size; (void)ws_size;

  _Float16* k16 = (_Float16*)((char*)d_ws + kWsK);
  _Float16* vt  = (_Float16*)((char*)d_ws + kWsV);
  float*    inv = (float*)((char*)d_ws + kWsInv);

  hipLaunchKernelGGL(cvt_k, dim3(kB * kTk * kD / (256 * 8)), dim3(256), 0, stream,
                     k, k16);
  hipLaunchKernelGGL(trans_v, dim3(kB * 64), dim3(256), 0, stream, v, vt);
  hipLaunchKernelGGL(k1_logits, dim3(2048), dim3(512), 0, stream,
                     q, k16, m, out, inv);
  hipLaunchKernelGGL(k2_score_pv, dim3(2048), dim3(512), 0, stream,
                     vt, inv, out);
}